// Round 7
// baseline (151.727 us; speedup 1.0000x reference)
//
#include <hip/hip_runtime.h>
#include <hip/hip_bf16.h>
#include <math.h>

#define Mm 400
#define Cc 8
#define Ww 100
#define Dd 300
#define Hh 100
#define Rr 25
#define MC 3200   // M*C
#define KP 320    // K padded to multiple of 32
#define LBP_ITERS 5
#define CTX_STRIDE 688   // bytes per LDS row (16-B aligned, 172 words -> spread banks)

typedef _Float16 f16x8 __attribute__((ext_vector_type(8)));
typedef _Float16 f16x4 __attribute__((ext_vector_type(4)));
typedef float f32x4 __attribute__((ext_vector_type(4)));

__device__ __forceinline__ void gload16(const void* g, void* l) {
  __builtin_amdgcn_global_load_lds(
      (const __attribute__((address_space(1))) void*)g,
      (__attribute__((address_space(3))) void*)l, 16, 0, 0);
}

// ---------------------------------------------------------------------------
// fp16 conversion: Ah = fp16(X*Cl), Bh = fp16(X), AhA = fp16(X*A).
// K padded 300->320 with zeros (k-pad MUST be zero: MFMA sums over k).
// ---------------------------------------------------------------------------
__global__ __launch_bounds__(256) void k_convert(
    const float* __restrict__ X,   // [MC][D] (cand_vec)
    const float* __restrict__ Cl,  // [D]
    const float* __restrict__ A,   // [D]
    _Float16* __restrict__ Ah,     // [MC][KP]
    _Float16* __restrict__ Bh,     // [MC][KP]
    _Float16* __restrict__ AhA)    // [MC][KP]
{
  int idx = blockIdx.x * 256 + threadIdx.x;
  if (idx >= MC * KP) return;
  int j = idx / KP, k = idx - j * KP;
  float x = 0.f, cl = 0.f, a = 0.f;
  if (k < Dd) { x = X[(size_t)j * Dd + k]; cl = Cl[k]; a = A[k]; }
  Bh[idx]  = (_Float16)x;
  Ah[idx]  = (_Float16)(x * cl);
  AhA[idx] = (_Float16)(x * a);
}

// ---------------------------------------------------------------------------
// k_u: u[m][w] = max_c <A*e_c, ctxt_w> via one 16x16x32 f16 MFMA chain.
// Grid (7 w-tiles, 400 mentions), 64 threads (1 wave). Short latency chain,
// 2800 blocks -> latency hidden by block-level parallelism.
// LDS rows padded to 688 B. Garbage rows (c>=8, w>=100) are confined by MFMA
// row/col independence to masked outputs; all k-pads are zero.
// ---------------------------------------------------------------------------
__global__ __launch_bounds__(64) void k_u(
    const float* __restrict__ ctxt_vec,    // [M][W][D]
    const _Float16* __restrict__ candA,    // [MC][KP] = fp16(cand*A), pads zero
    float* __restrict__ u)                 // [M][128]
{
  const int bx = blockIdx.x, m = blockIdx.y;
  const int w0 = bx * 16;
  const int tid = threadIdx.x;
  const int fr = tid & 15, fq = tid >> 4;
  __shared__ __align__(16) _Float16 candH[16 * (CTX_STRIDE / 2)];
  __shared__ __align__(16) _Float16 ctxtH[16 * (CTX_STRIDE / 2)];

  // stage cand: 8 rows x 40 f16x8 chunks, direct fp16 copy (pads already 0)
  const _Float16* ca = candA + (size_t)m * Cc * KP;
#pragma unroll
  for (int e = tid; e < 320; e += 64) {
    int r = e / 40, j = e - r * 40;
    f16x8 v = *(const f16x8*)(ca + r * KP + j * 8);
    *(f16x8*)((char*)candH + r * CTX_STRIDE + j * 16) = v;
  }
  // stage ctxt rows w0..w0+nr-1 fp32->fp16
  const float* cw = ctxt_vec + (size_t)m * Ww * Dd;
  const int nr = (w0 + 16 <= Ww) ? 16 : (Ww - w0);
  for (int e = tid; e < nr * 75; e += 64) {
    int r = e / 75, j = e - r * 75;
    float4 v = *(const float4*)(cw + (size_t)(w0 + r) * Dd + j * 4);
    f16x4 h = { (_Float16)v.x, (_Float16)v.y, (_Float16)v.z, (_Float16)v.w };
    *(f16x4*)((char*)ctxtH + r * CTX_STRIDE + j * 8) = h;
  }
  // zero k-pad (bytes 600..640) of the valid ctxt rows
  for (int e = tid; e < nr * 5; e += 64) {
    int r = e / 5, q = e - r * 5;
    f16x4 z = {};
    *(f16x4*)((char*)ctxtH + r * CTX_STRIDE + 600 + q * 8) = z;
  }
  __syncthreads();

  f32x4 acc = {};
#pragma unroll
  for (int s = 0; s < 10; ++s) {
    int kb = s * 64 + fq * 16;
    f16x8 af = *(const f16x8*)((const char*)candH + fr * CTX_STRIDE + kb);
    f16x8 bf = *(const f16x8*)((const char*)ctxtH + fr * CTX_STRIDE + kb);
    acc = __builtin_amdgcn_mfma_f32_16x16x32_f16(af, bf, acc, 0, 0, 0);
  }
  // D: col(w)=lane&15, row(c)=fq*4+reg; valid c rows 0..7 => fq<2
  float v0 = fmaxf(fmaxf(acc[0], acc[1]), fmaxf(acc[2], acc[3]));
  if (fq >= 2) v0 = -1e30f;
  v0 = fmaxf(v0, __shfl_xor(v0, 16));
  if (fq == 0 && (w0 + fr) < Ww) u[m * 128 + w0 + fr] = v0;
}

// ---------------------------------------------------------------------------
// k_escore: per mention: topk(25, with multiplicity) -> softmax beta ->
// ctxt_full (fp32 coalesced) -> scores. Tiny LDS -> 8 blocks/CU.
// ---------------------------------------------------------------------------
__global__ __launch_bounds__(256) void k_escore(
    const float* __restrict__ u,          // [M][128]
    const float* __restrict__ ctxt_vec,   // [M][W][D]
    const float* __restrict__ cand_vec,   // [M][C][D]
    const float* __restrict__ B,          // [D]
    float* __restrict__ scores,           // [MC]
    float* __restrict__ col0)             // [MC]
{
  const int m = blockIdx.x;
  const int tid = threadIdx.x;
  __shared__ float u_s[Ww];
  __shared__ float beta_s[Ww];
  __shared__ __align__(16) float cf_part[3 * 300];
  __shared__ __align__(16) float cfB[304];

  const float* cw  = ctxt_vec + (size_t)m * Ww * Dd;
  const float* cev = cand_vec + (size_t)m * Cc * Dd;

  if (tid < Ww) u_s[tid] = u[m * 128 + tid];
  __syncthreads();

  // topk + threshold + softmax, wave 0 in registers
  if (tid < 64) {
    float a0 = u_s[tid];
    float a1 = (tid + 64 < Ww) ? u_s[tid + 64] : -1e30f;
    float q0 = a0, q1 = a1, sketch = 0.f;
    for (int r = 0; r < Rr; ++r) {
      float v; int idx;
      if (q1 > q0) { v = q1; idx = tid + 64; } else { v = q0; idx = tid; }
#pragma unroll
      for (int off = 1; off < 64; off <<= 1) {
        float ov = __shfl_xor(v, off);
        int   oi = __shfl_xor(idx, off);
        if (ov > v || (ov == v && oi < idx)) { v = ov; idx = oi; }
      }
      sketch = v;
      if (idx == tid) q0 = -1e30f;
      else if (idx == tid + 64) q1 = -1e30f;
    }
    float m0 = (a0 > sketch) ? a0 : sketch - 50.0f;
    float m1 = (tid + 64 < Ww) ? ((a1 > sketch) ? a1 : sketch - 50.0f) : -1e30f;
    float mx = fmaxf(m0, m1);
#pragma unroll
    for (int off = 1; off < 64; off <<= 1) mx = fmaxf(mx, __shfl_xor(mx, off));
    float e0 = expf(m0 - mx);
    float e1 = (tid + 64 < Ww) ? expf(m1 - mx) : 0.f;
    float s = e0 + e1;
#pragma unroll
    for (int off = 1; off < 64; off <<= 1) s += __shfl_xor(s, off);
    float inv = 1.0f / s;
    beta_s[tid] = e0 * inv;
    if (tid + 64 < Ww) beta_s[tid + 64] = e1 * inv;
  }
  __syncthreads();

  // ctxt_full partials: 3 w-groups x 75 d4-columns, coalesced float4
  if (tid < 225) {
    int tg = tid / 75, d4 = tid - tg * 75;
    f32x4 cf = {};
    for (int w = tg; w < Ww; w += 3) {
      float4 x = *(const float4*)(cw + (size_t)w * Dd + d4 * 4);
      float bw = beta_s[w];
      cf[0] += bw * x.x; cf[1] += bw * x.y; cf[2] += bw * x.z; cf[3] += bw * x.w;
    }
    *(f32x4*)&cf_part[(tg * 75 + d4) * 4] = cf;
  }
  __syncthreads();

  if (tid < 75) {
    f32x4 s4 = *(const f32x4*)&cf_part[tid * 4];
    s4 += *(const f32x4*)&cf_part[(75 + tid) * 4];
    s4 += *(const f32x4*)&cf_part[(150 + tid) * 4];
    float4 b4 = *(const float4*)(B + tid * 4);
    s4[0] *= b4.x; s4[1] *= b4.y; s4[2] *= b4.z; s4[3] *= b4.w;
    *(f32x4*)&cfB[tid * 4] = s4;
  }
  __syncthreads();

  if (tid < 128) {
    int c = tid >> 4, l = tid & 15;
    float p = 0.f;
    for (int d4 = l; d4 < 75; d4 += 16) {
      float4 x = *(const float4*)(cev + (size_t)c * Dd + d4 * 4);
      f32x4 f = *(const f32x4*)&cfB[d4 * 4];
      p += x.x * f[0] + x.y * f[1] + x.z * f[2] + x.w * f[3];
    }
#pragma unroll
    for (int off = 8; off; off >>= 1) p += __shfl_down(p, off, 16);
    if (l == 0) { scores[m * Cc + c] = p; col0[m * Cc + c] = p; }
  }
}

// ---------------------------------------------------------------------------
// Kernel 2: P = Ah @ Bh^T  [3200 x 3200], K=320, fp16 MFMA, fp32 accum,
// fp16 output via LDS-staged coalesced epilogue.
// ---------------------------------------------------------------------------
__global__ __launch_bounds__(256) void k_pairwise_mfma(
    const _Float16* __restrict__ Ah,  // [MC][KP]
    const _Float16* __restrict__ Bh,  // [MC][KP]
    _Float16* __restrict__ P)         // [MC][MC] fp16
{
  __shared__ __align__(16) _Float16 Sh[2][128 * 32];
  const int tid = threadIdx.x;
  const int wave = tid >> 6, lane = tid & 63;
  const int wr = wave >> 1, wc = wave & 1;
  const int row0 = blockIdx.y * 128, col0 = blockIdx.x * 128;

  f32x4 acc[4][4] = {};
  const int fr = lane & 15, fq = lane >> 4;
  const int koff = fq * 8;

  for (int kt = 0; kt < KP / 32; ++kt) {
    const int k0 = kt * 32;
#pragma unroll
    for (int i = 0; i < 2; ++i) {
      int e = i * 256 + tid;
      int r = e >> 2;
      int kc = (e & 3) << 3;
      gload16(Ah + (size_t)(row0 + r) * KP + k0 + kc, (char*)Sh[0] + e * 16);
      gload16(Bh + (size_t)(col0 + r) * KP + k0 + kc, (char*)Sh[1] + e * 16);
    }
    __syncthreads();

    f16x8 af[4], bfr[4];
#pragma unroll
    for (int mi = 0; mi < 4; ++mi)
      af[mi] = *(const f16x8*)&Sh[0][(wr * 64 + mi * 16 + fr) * 32 + koff];
#pragma unroll
    for (int ni = 0; ni < 4; ++ni)
      bfr[ni] = *(const f16x8*)&Sh[1][(wc * 64 + ni * 16 + fr) * 32 + koff];
#pragma unroll
    for (int mi = 0; mi < 4; ++mi)
#pragma unroll
      for (int ni = 0; ni < 4; ++ni)
        acc[mi][ni] = __builtin_amdgcn_mfma_f32_16x16x32_f16(
            af[mi], bfr[ni], acc[mi][ni], 0, 0, 0);
    __syncthreads();
  }

  _Float16* wtile = (_Float16*)((char*)Sh + wave * 4096);
#pragma unroll
  for (int h = 0; h < 2; ++h) {
    __syncthreads();
#pragma unroll
    for (int mi2 = 0; mi2 < 2; ++mi2) {
      int mi = h * 2 + mi2;
#pragma unroll
      for (int ni = 0; ni < 4; ++ni)
#pragma unroll
        for (int r = 0; r < 4; ++r)
          wtile[(mi2 * 16 + fq * 4 + r) * 64 + ni * 16 + fr] =
              (_Float16)acc[mi][ni][r];
    }
    __syncthreads();
#pragma unroll
    for (int t = 0; t < 4; ++t) {
      int q = t * 64 + lane;
      int lr = q >> 3, lc8 = (q & 7) * 8;
      f16x8 v = *(const f16x8*)&wtile[lr * 64 + lc8];
      size_t gr = (size_t)(row0 + wr * 64 + h * 32 + lr);
      size_t gc = (size_t)(col0 + wc * 64 + lc8);
      *(f16x8*)(P + gr * MC + gc) = v;
    }
  }
}

// ---------------------------------------------------------------------------
// LBP step in exp-space: emsg stores exp(msg). Reuses softmax numerators:
// exp(sel) = e_b / se.  iter 0: old = exp(0) = 1 (no memset needed).
//   emsg_new = 0.5*(self ? 1 : e_b/se) + 0.5*emsg_old
//   psum += log(emsg_new)   (= msg, for the column sums)
// ---------------------------------------------------------------------------
__global__ __launch_bounds__(256) void k_lbp(
    const _Float16* __restrict__ P,
    const float* __restrict__ colIn,
    const float* __restrict__ scores,
    float* __restrict__ emsg,
    float* __restrict__ colOut,
    int first)
{
  const int aa = blockIdx.x;
  __shared__ __align__(16) float col_s[MC];
  __shared__ float red_s[4][Cc];
  for (int i = threadIdx.x; i < MC; i += 256) col_s[i] = colIn[i];
  __syncthreads();

  float psum[Cc];
#pragma unroll
  for (int b = 0; b < Cc; ++b) psum[b] = 0.f;

  for (int m = threadIdx.x; m < Mm; m += 256) {
    const float4 c0 = *reinterpret_cast<const float4*>(&col_s[m * 8]);
    const float4 c1 = *reinterpret_cast<const float4*>(&col_s[m * 8 + 4]);
    float t[Cc];
#pragma unroll
    for (int b = 0; b < Cc; ++b) {
      f16x8 ph = *(const f16x8*)(P + (size_t)(aa * 8 + b) * MC + m * 8);
      float tb = fmaxf(fmaxf((float)ph[0] + c0.x, (float)ph[1] + c0.y),
                       fmaxf((float)ph[2] + c0.z, (float)ph[3] + c0.w));
      t[b] = fmaxf(tb, fmaxf(fmaxf((float)ph[4] + c1.x, (float)ph[5] + c1.y),
                             fmaxf((float)ph[6] + c1.z, (float)ph[7] + c1.w)));
    }
    float mxt = t[0];
#pragma unroll
    for (int b = 1; b < Cc; ++b) mxt = fmaxf(mxt, t[b]);
    float se = 0.f;
#pragma unroll
    for (int b = 0; b < Cc; ++b) { float eb = expf(t[b] - mxt); t[b] = eb; se += eb; }
    float inv_se = 1.0f / se;
    bool self = (m == aa);
#pragma unroll
    for (int b = 0; b < Cc; ++b) {
      float sel_e = self ? 1.0f : t[b] * inv_se;
      size_t mi = (size_t)(aa * 8 + b) * Mm + m;
      float old_e = first ? 1.0f : emsg[mi];
      float nv = 0.5f * sel_e + 0.5f * old_e;
      emsg[mi] = nv;
      psum[b] += logf(nv);
    }
  }

  const int wave = threadIdx.x >> 6, lane = threadIdx.x & 63;
#pragma unroll
  for (int b = 0; b < Cc; ++b)
#pragma unroll
    for (int off = 32; off; off >>= 1) psum[b] += __shfl_down(psum[b], off);
  if (lane == 0)
#pragma unroll
    for (int b = 0; b < Cc; ++b) red_s[wave][b] = psum[b];
  __syncthreads();
  if (threadIdx.x < Cc) {
    int b = threadIdx.x;
    float s = red_s[0][b] + red_s[1][b] + red_s[2][b] + red_s[3][b];
    colOut[aa * Cc + b] = scores[aa * Cc + b] + s;
  }
}

// ---------------------------------------------------------------------------
// Final: fgs = log_softmax(colF, axis=C); tiny MLP. One thread per mention.
// ---------------------------------------------------------------------------
__global__ __launch_bounds__(64) void k_final2(
    const float* __restrict__ colF,
    const float* __restrict__ pem,
    const float* __restrict__ W1,
    const float* __restrict__ b1,
    const float* __restrict__ W2,
    const float* __restrict__ b2,
    float* __restrict__ out)
{
  int m = blockIdx.x * 64 + threadIdx.x;
  if (m >= Mm) return;
  float f[Cc], pm[Cc];
#pragma unroll
  for (int c = 0; c < Cc; ++c) {
    f[c] = colF[m * Cc + c];
    pm[c] = pem[m * Cc + c];
  }
  float mx = f[0];
#pragma unroll
  for (int c = 1; c < Cc; ++c) mx = fmaxf(mx, f[c]);
  float se = 0.f;
#pragma unroll
  for (int c = 0; c < Cc; ++c) se += expf(f[c] - mx);
  float lse = mx + logf(se);
  float fgs[Cc], accv[Cc];
  float bb2 = b2[0];
#pragma unroll
  for (int c = 0; c < Cc; ++c) { fgs[c] = f[c] - lse; accv[c] = bb2; }
  for (int h = 0; h < Hh; ++h) {
    float w0 = W1[2 * h], w1 = W1[2 * h + 1], bb = b1[h], w2 = W2[h];
#pragma unroll
    for (int c = 0; c < Cc; ++c)
      accv[c] += w2 * fmaxf(fgs[c] * w0 + pm[c] * w1 + bb, 0.f);
  }
#pragma unroll
  for (int c = 0; c < Cc; ++c) out[m * Cc + c] = accv[c];
}

// ---------------------------------------------------------------------------
extern "C" void kernel_launch(void* const* d_in, const int* in_sizes, int n_in,
                              void* d_out, int out_size, void* d_ws, size_t ws_size,
                              hipStream_t stream) {
  const float* ctxt_vec = (const float*)d_in[1];   // [M][W][D]
  const float* cand_vec = (const float*)d_in[3];   // [M][C][D]
  const float* pem      = (const float*)d_in[4];   // [M][C]
  const float* A        = (const float*)d_in[5];
  const float* B        = (const float*)d_in[6];
  const float* Cl       = (const float*)d_in[7];
  const float* W1       = (const float*)d_in[8];
  const float* b1       = (const float*)d_in[9];
  const float* W2       = (const float*)d_in[10];
  const float* b2       = (const float*)d_in[11];
  float* out = (float*)d_out;

  char* ws = (char*)d_ws;
  _Float16* P     = (_Float16*)(ws);                      // 20,480,000 B
  float*   emsg   = (float*)(ws + 20480000);              //  5,120,000 B
  // Ah/Bh alias the emsg region (live only until GEMM; emsg written after)
  _Float16* Ah    = (_Float16*)(ws + 20480000);           //  2,048,000 B
  _Float16* Bh    = (_Float16*)(ws + 20480000 + 2048000); //  2,048,000 B
  // AhA aliases P (consumed by k_u, which completes before the GEMM writes P)
  _Float16* AhA   = (_Float16*)(ws);                      //  2,048,000 B
  float*   scores = (float*)(ws + 25600000);
  float*   col0   = scores + MC;
  float*   col1   = col0 + MC;
  float*   u      = (float*)(ws + 25700000);              //  204,800 B

  k_convert<<<(MC * KP + 255) / 256, 256, 0, stream>>>(cand_vec, Cl, A, Ah, Bh, AhA);
  k_u<<<dim3(7, Mm), 64, 0, stream>>>(ctxt_vec, AhA, u);
  k_escore<<<Mm, 256, 0, stream>>>(u, ctxt_vec, cand_vec, B, scores, col0);

  dim3 g(MC / 128, MC / 128);
  k_pairwise_mfma<<<g, 256, 0, stream>>>(Ah, Bh, P);

  float* cIn = col0; float* cOut = col1;
  for (int it = 0; it < LBP_ITERS; ++it) {
    k_lbp<<<Mm, 256, 0, stream>>>(P, cIn, scores, emsg, cOut, it == 0 ? 1 : 0);
    float* t = cIn; cIn = cOut; cOut = t;
  }
  k_final2<<<(Mm + 63) / 64, 64, 0, stream>>>(cIn, pem, W1, b1, W2, b2, out);
}

// Round 8
// 133.403 us; speedup vs baseline: 1.1374x; 1.1374x over previous
//
#include <hip/hip_runtime.h>
#include <hip/hip_bf16.h>
#include <math.h>

#define Mm 400
#define Cc 8
#define Ww 100
#define Dd 300
#define Hh 100
#define Rr 25
#define MC 3200   // M*C
#define KP 320    // K padded to multiple of 32
#define LBP_ITERS 5
#define CTX_STRIDE 688   // bytes per LDS row in k_u

typedef _Float16 f16x8 __attribute__((ext_vector_type(8)));
typedef _Float16 f16x4 __attribute__((ext_vector_type(4)));
typedef float f32x4 __attribute__((ext_vector_type(4)));

__device__ __forceinline__ void gload16(const void* g, void* l) {
  __builtin_amdgcn_global_load_lds(
      (const __attribute__((address_space(1))) void*)g,
      (__attribute__((address_space(3))) void*)l, 16, 0, 0);
}

// ---------------------------------------------------------------------------
// fp16 conversion: Ah = fp16(X*Cl), Bh = fp16(X), AhA = fp16(X*A).
// K padded 300->320 with zeros (k-pad MUST be zero: MFMA sums over k).
// ---------------------------------------------------------------------------
__global__ __launch_bounds__(256) void k_convert(
    const float* __restrict__ X,   // [MC][D] (cand_vec)
    const float* __restrict__ Cl,  // [D]
    const float* __restrict__ A,   // [D]
    _Float16* __restrict__ Ah,     // [MC][KP]
    _Float16* __restrict__ Bh,     // [MC][KP]
    _Float16* __restrict__ AhA)    // [MC][KP]
{
  int idx = blockIdx.x * 256 + threadIdx.x;
  if (idx >= MC * KP) return;
  int j = idx / KP, k = idx - j * KP;
  float x = 0.f, cl = 0.f, a = 0.f;
  if (k < Dd) { x = X[(size_t)j * Dd + k]; cl = Cl[k]; a = A[k]; }
  Bh[idx]  = (_Float16)x;
  Ah[idx]  = (_Float16)(x * cl);
  AhA[idx] = (_Float16)(x * a);
}

// ---------------------------------------------------------------------------
// k_u: u[m][w] = max_c <A*e_c, ctxt_w> via one 16x16x32 f16 MFMA chain.
// Grid (7 w-tiles, 400 mentions), 64 threads.
// ---------------------------------------------------------------------------
__global__ __launch_bounds__(64) void k_u(
    const float* __restrict__ ctxt_vec,    // [M][W][D]
    const _Float16* __restrict__ candA,    // [MC][KP] = fp16(cand*A), pads zero
    float* __restrict__ u)                 // [M][128]
{
  const int bx = blockIdx.x, m = blockIdx.y;
  const int w0 = bx * 16;
  const int tid = threadIdx.x;
  const int fr = tid & 15, fq = tid >> 4;
  __shared__ __align__(16) _Float16 candH[16 * (CTX_STRIDE / 2)];
  __shared__ __align__(16) _Float16 ctxtH[16 * (CTX_STRIDE / 2)];

  const _Float16* ca = candA + (size_t)m * Cc * KP;
#pragma unroll
  for (int e = tid; e < 320; e += 64) {
    int r = e / 40, j = e - r * 40;
    f16x8 v = *(const f16x8*)(ca + r * KP + j * 8);
    *(f16x8*)((char*)candH + r * CTX_STRIDE + j * 16) = v;
  }
  const float* cw = ctxt_vec + (size_t)m * Ww * Dd;
  const int nr = (w0 + 16 <= Ww) ? 16 : (Ww - w0);
  for (int e = tid; e < nr * 75; e += 64) {
    int r = e / 75, j = e - r * 75;
    float4 v = *(const float4*)(cw + (size_t)(w0 + r) * Dd + j * 4);
    f16x4 h = { (_Float16)v.x, (_Float16)v.y, (_Float16)v.z, (_Float16)v.w };
    *(f16x4*)((char*)ctxtH + r * CTX_STRIDE + j * 8) = h;
  }
  for (int e = tid; e < nr * 5; e += 64) {
    int r = e / 5, q = e - r * 5;
    f16x4 z = {};
    *(f16x4*)((char*)ctxtH + r * CTX_STRIDE + 600 + q * 8) = z;
  }
  __syncthreads();

  f32x4 acc = {};
#pragma unroll
  for (int s = 0; s < 10; ++s) {
    int kb = s * 64 + fq * 16;
    f16x8 af = *(const f16x8*)((const char*)candH + fr * CTX_STRIDE + kb);
    f16x8 bf = *(const f16x8*)((const char*)ctxtH + fr * CTX_STRIDE + kb);
    acc = __builtin_amdgcn_mfma_f32_16x16x32_f16(af, bf, acc, 0, 0, 0);
  }
  float v0 = fmaxf(fmaxf(acc[0], acc[1]), fmaxf(acc[2], acc[3]));
  if (fq >= 2) v0 = -1e30f;
  v0 = fmaxf(v0, __shfl_xor(v0, 16));
  if (fq == 0 && (w0 + fr) < Ww) u[m * 128 + w0 + fr] = v0;
}

// ---------------------------------------------------------------------------
// k_escore: per mention: topk(25 w/ multiplicity) -> softmax beta ->
// ctxt_full (fp32 coalesced) -> scores.
// ---------------------------------------------------------------------------
__global__ __launch_bounds__(256) void k_escore(
    const float* __restrict__ u,          // [M][128]
    const float* __restrict__ ctxt_vec,   // [M][W][D]
    const float* __restrict__ cand_vec,   // [M][C][D]
    const float* __restrict__ B,          // [D]
    float* __restrict__ scores)           // [MC]
{
  const int m = blockIdx.x;
  const int tid = threadIdx.x;
  __shared__ float u_s[Ww];
  __shared__ float beta_s[Ww];
  __shared__ __align__(16) float cf_part[3 * 300];
  __shared__ __align__(16) float cfB[304];

  const float* cw  = ctxt_vec + (size_t)m * Ww * Dd;
  const float* cev = cand_vec + (size_t)m * Cc * Dd;

  if (tid < Ww) u_s[tid] = u[m * 128 + tid];
  __syncthreads();

  if (tid < 64) {
    float a0 = u_s[tid];
    float a1 = (tid + 64 < Ww) ? u_s[tid + 64] : -1e30f;
    float q0 = a0, q1 = a1, sketch = 0.f;
    for (int r = 0; r < Rr; ++r) {
      float v; int idx;
      if (q1 > q0) { v = q1; idx = tid + 64; } else { v = q0; idx = tid; }
#pragma unroll
      for (int off = 1; off < 64; off <<= 1) {
        float ov = __shfl_xor(v, off);
        int   oi = __shfl_xor(idx, off);
        if (ov > v || (ov == v && oi < idx)) { v = ov; idx = oi; }
      }
      sketch = v;
      if (idx == tid) q0 = -1e30f;
      else if (idx == tid + 64) q1 = -1e30f;
    }
    float m0 = (a0 > sketch) ? a0 : sketch - 50.0f;
    float m1 = (tid + 64 < Ww) ? ((a1 > sketch) ? a1 : sketch - 50.0f) : -1e30f;
    float mx = fmaxf(m0, m1);
#pragma unroll
    for (int off = 1; off < 64; off <<= 1) mx = fmaxf(mx, __shfl_xor(mx, off));
    float e0 = expf(m0 - mx);
    float e1 = (tid + 64 < Ww) ? expf(m1 - mx) : 0.f;
    float s = e0 + e1;
#pragma unroll
    for (int off = 1; off < 64; off <<= 1) s += __shfl_xor(s, off);
    float inv = 1.0f / s;
    beta_s[tid] = e0 * inv;
    if (tid + 64 < Ww) beta_s[tid + 64] = e1 * inv;
  }
  __syncthreads();

  if (tid < 225) {
    int tg = tid / 75, d4 = tid - tg * 75;
    f32x4 cf = {};
    for (int w = tg; w < Ww; w += 3) {
      float4 x = *(const float4*)(cw + (size_t)w * Dd + d4 * 4);
      float bw = beta_s[w];
      cf[0] += bw * x.x; cf[1] += bw * x.y; cf[2] += bw * x.z; cf[3] += bw * x.w;
    }
    *(f32x4*)&cf_part[(tg * 75 + d4) * 4] = cf;
  }
  __syncthreads();

  if (tid < 75) {
    f32x4 s4 = *(const f32x4*)&cf_part[tid * 4];
    s4 += *(const f32x4*)&cf_part[(75 + tid) * 4];
    s4 += *(const f32x4*)&cf_part[(150 + tid) * 4];
    float4 b4 = *(const float4*)(B + tid * 4);
    s4[0] *= b4.x; s4[1] *= b4.y; s4[2] *= b4.z; s4[3] *= b4.w;
    *(f32x4*)&cfB[tid * 4] = s4;
  }
  __syncthreads();

  if (tid < 128) {
    int c = tid >> 4, l = tid & 15;
    float p = 0.f;
    for (int d4 = l; d4 < 75; d4 += 16) {
      float4 x = *(const float4*)(cev + (size_t)c * Dd + d4 * 4);
      f32x4 f = *(const f32x4*)&cfB[d4 * 4];
      p += x.x * f[0] + x.y * f[1] + x.z * f[2] + x.w * f[3];
    }
#pragma unroll
    for (int off = 8; off; off >>= 1) p += __shfl_down(p, off, 16);
    if (l == 0) scores[m * Cc + c] = p;
  }
}

// ---------------------------------------------------------------------------
// Kernel 2: P = Ah @ Bh^T  [3200 x 3200], K=320, fp16 MFMA, fp32 accum,
// fp16 output via LDS-staged coalesced epilogue.
// ---------------------------------------------------------------------------
__global__ __launch_bounds__(256) void k_pairwise_mfma(
    const _Float16* __restrict__ Ah,  // [MC][KP]
    const _Float16* __restrict__ Bh,  // [MC][KP]
    _Float16* __restrict__ P)         // [MC][MC] fp16
{
  __shared__ __align__(16) _Float16 Sh[2][128 * 32];
  const int tid = threadIdx.x;
  const int wave = tid >> 6, lane = tid & 63;
  const int wr = wave >> 1, wc = wave & 1;
  const int row0 = blockIdx.y * 128, col0 = blockIdx.x * 128;

  f32x4 acc[4][4] = {};
  const int fr = lane & 15, fq = lane >> 4;
  const int koff = fq * 8;

  for (int kt = 0; kt < KP / 32; ++kt) {
    const int k0 = kt * 32;
#pragma unroll
    for (int i = 0; i < 2; ++i) {
      int e = i * 256 + tid;
      int r = e >> 2;
      int kc = (e & 3) << 3;
      gload16(Ah + (size_t)(row0 + r) * KP + k0 + kc, (char*)Sh[0] + e * 16);
      gload16(Bh + (size_t)(col0 + r) * KP + k0 + kc, (char*)Sh[1] + e * 16);
    }
    __syncthreads();

    f16x8 af[4], bfr[4];
#pragma unroll
    for (int mi = 0; mi < 4; ++mi)
      af[mi] = *(const f16x8*)&Sh[0][(wr * 64 + mi * 16 + fr) * 32 + koff];
#pragma unroll
    for (int ni = 0; ni < 4; ++ni)
      bfr[ni] = *(const f16x8*)&Sh[1][(wc * 64 + ni * 16 + fr) * 32 + koff];
#pragma unroll
    for (int mi = 0; mi < 4; ++mi)
#pragma unroll
      for (int ni = 0; ni < 4; ++ni)
        acc[mi][ni] = __builtin_amdgcn_mfma_f32_16x16x32_f16(
            af[mi], bfr[ni], acc[mi][ni], 0, 0, 0);
    __syncthreads();
  }

  _Float16* wtile = (_Float16*)((char*)Sh + wave * 4096);
#pragma unroll
  for (int h = 0; h < 2; ++h) {
    __syncthreads();
#pragma unroll
    for (int mi2 = 0; mi2 < 2; ++mi2) {
      int mi = h * 2 + mi2;
#pragma unroll
      for (int ni = 0; ni < 4; ++ni)
#pragma unroll
        for (int r = 0; r < 4; ++r)
          wtile[(mi2 * 16 + fq * 4 + r) * 64 + ni * 16 + fr] =
              (_Float16)acc[mi][ni][r];
    }
    __syncthreads();
#pragma unroll
    for (int t = 0; t < 4; ++t) {
      int q = t * 64 + lane;
      int lr = q >> 3, lc8 = (q & 7) * 8;
      f16x8 v = *(const f16x8*)&wtile[lr * 64 + lc8];
      size_t gr = (size_t)(row0 + wr * 64 + h * 32 + lr);
      size_t gc = (size_t)(col0 + wc * 64 + lc8);
      *(f16x8*)(P + gr * MC + gc) = v;
    }
  }
}

// ---------------------------------------------------------------------------
// LBP step, exp-space, m-split for occupancy. Grid (Mm, 2): half handles
// 200 m (one per thread). Column sums are PARTIAL (no scores):
//   pOut[half][aa*8+b] = sum_{m in half} log(emsg_new)
// Next iter assembles col = scores + pIn0 + pIn1 (ping-pong buffers).
// ---------------------------------------------------------------------------
__global__ __launch_bounds__(256) void k_lbp(
    const _Float16* __restrict__ P,
    const float* __restrict__ scores,
    const float* __restrict__ pIn0,   // [MC] prev partial half 0
    const float* __restrict__ pIn1,   // [MC] prev partial half 1
    float* __restrict__ pOut,         // [2][MC] this iter's partials
    float* __restrict__ emsg,
    int first)
{
  const int aa = blockIdx.x, half = blockIdx.y;
  const int tid = threadIdx.x;
  __shared__ __align__(16) float col_s[MC];
  __shared__ float red_s[4][Cc];

  if (first) {
    for (int i = tid; i < MC / 4; i += 256)
      *(f32x4*)&col_s[i * 4] = *(const f32x4*)&scores[i * 4];
  } else {
    for (int i = tid; i < MC / 4; i += 256) {
      f32x4 v = *(const f32x4*)&scores[i * 4];
      v += *(const f32x4*)&pIn0[i * 4];
      v += *(const f32x4*)&pIn1[i * 4];
      *(f32x4*)&col_s[i * 4] = v;
    }
  }
  __syncthreads();

  float psum[Cc];
#pragma unroll
  for (int b = 0; b < Cc; ++b) psum[b] = 0.f;

  const int m = half * 200 + tid;
  if (tid < 200) {
    const float4 c0 = *reinterpret_cast<const float4*>(&col_s[m * 8]);
    const float4 c1 = *reinterpret_cast<const float4*>(&col_s[m * 8 + 4]);
    float t[Cc];
#pragma unroll
    for (int b = 0; b < Cc; ++b) {
      f16x8 ph = *(const f16x8*)(P + (size_t)(aa * 8 + b) * MC + m * 8);
      float tb = fmaxf(fmaxf((float)ph[0] + c0.x, (float)ph[1] + c0.y),
                       fmaxf((float)ph[2] + c0.z, (float)ph[3] + c0.w));
      t[b] = fmaxf(tb, fmaxf(fmaxf((float)ph[4] + c1.x, (float)ph[5] + c1.y),
                             fmaxf((float)ph[6] + c1.z, (float)ph[7] + c1.w)));
    }
    float mxt = t[0];
#pragma unroll
    for (int b = 1; b < Cc; ++b) mxt = fmaxf(mxt, t[b]);
    float se = 0.f;
#pragma unroll
    for (int b = 0; b < Cc; ++b) { float eb = expf(t[b] - mxt); t[b] = eb; se += eb; }
    float inv_se = 1.0f / se;
    bool self = (m == aa);
#pragma unroll
    for (int b = 0; b < Cc; ++b) {
      float sel_e = self ? 1.0f : t[b] * inv_se;
      size_t mi = (size_t)(aa * 8 + b) * Mm + m;
      float old_e = first ? 1.0f : emsg[mi];
      float nv = 0.5f * sel_e + 0.5f * old_e;
      emsg[mi] = nv;
      psum[b] += logf(nv);
    }
  }

  const int wave = tid >> 6, lane = tid & 63;
#pragma unroll
  for (int b = 0; b < Cc; ++b)
#pragma unroll
    for (int off = 32; off; off >>= 1) psum[b] += __shfl_down(psum[b], off);
  if (lane == 0)
#pragma unroll
    for (int b = 0; b < Cc; ++b) red_s[wave][b] = psum[b];
  __syncthreads();
  if (tid < Cc) {
    int b = tid;
    float s = red_s[0][b] + red_s[1][b] + red_s[2][b] + red_s[3][b];
    pOut[half * MC + aa * Cc + b] = s;
  }
}

// ---------------------------------------------------------------------------
// Final: colF = scores + p0 + p1; fgs = log_softmax(colF, axis=C); tiny MLP.
// ---------------------------------------------------------------------------
__global__ __launch_bounds__(64) void k_final2(
    const float* __restrict__ scores,
    const float* __restrict__ p0,
    const float* __restrict__ p1,
    const float* __restrict__ pem,
    const float* __restrict__ W1,
    const float* __restrict__ b1,
    const float* __restrict__ W2,
    const float* __restrict__ b2,
    float* __restrict__ out)
{
  int m = blockIdx.x * 64 + threadIdx.x;
  if (m >= Mm) return;
  float f[Cc], pm[Cc];
#pragma unroll
  for (int c = 0; c < Cc; ++c) {
    int j = m * Cc + c;
    f[c] = scores[j] + p0[j] + p1[j];
    pm[c] = pem[j];
  }
  float mx = f[0];
#pragma unroll
  for (int c = 1; c < Cc; ++c) mx = fmaxf(mx, f[c]);
  float se = 0.f;
#pragma unroll
  for (int c = 0; c < Cc; ++c) se += expf(f[c] - mx);
  float lse = mx + logf(se);
  float fgs[Cc], accv[Cc];
  float bb2 = b2[0];
#pragma unroll
  for (int c = 0; c < Cc; ++c) { fgs[c] = f[c] - lse; accv[c] = bb2; }
  for (int h = 0; h < Hh; ++h) {
    float w0 = W1[2 * h], w1 = W1[2 * h + 1], bb = b1[h], w2 = W2[h];
#pragma unroll
    for (int c = 0; c < Cc; ++c)
      accv[c] += w2 * fmaxf(fgs[c] * w0 + pm[c] * w1 + bb, 0.f);
  }
#pragma unroll
  for (int c = 0; c < Cc; ++c) out[m * Cc + c] = accv[c];
}

// ---------------------------------------------------------------------------
extern "C" void kernel_launch(void* const* d_in, const int* in_sizes, int n_in,
                              void* d_out, int out_size, void* d_ws, size_t ws_size,
                              hipStream_t stream) {
  const float* ctxt_vec = (const float*)d_in[1];   // [M][W][D]
  const float* cand_vec = (const float*)d_in[3];   // [M][C][D]
  const float* pem      = (const float*)d_in[4];   // [M][C]
  const float* A        = (const float*)d_in[5];
  const float* B        = (const float*)d_in[6];
  const float* Cl       = (const float*)d_in[7];
  const float* W1       = (const float*)d_in[8];
  const float* b1       = (const float*)d_in[9];
  const float* W2       = (const float*)d_in[10];
  const float* b2       = (const float*)d_in[11];
  float* out = (float*)d_out;

  char* ws = (char*)d_ws;
  _Float16* P     = (_Float16*)(ws);                      // 20,480,000 B
  float*   emsg   = (float*)(ws + 20480000);              //  5,120,000 B
  // Ah/Bh alias the emsg region (live only until GEMM; emsg written after)
  _Float16* Ah    = (_Float16*)(ws + 20480000);           //  2,048,000 B
  _Float16* Bh    = (_Float16*)(ws + 20480000 + 2048000); //  2,048,000 B
  // AhA aliases P (consumed by k_u, which completes before the GEMM writes P)
  _Float16* AhA   = (_Float16*)(ws);                      //  2,048,000 B
  float*   scores = (float*)(ws + 25600000);              //     12,800 B
  float*   ppA    = (float*)(ws + 25612800);              //     25,600 B [2][MC]
  float*   ppB    = (float*)(ws + 25638400);              //     25,600 B [2][MC]
  float*   u      = (float*)(ws + 25700000);              //    204,800 B

  k_convert<<<(MC * KP + 255) / 256, 256, 0, stream>>>(cand_vec, Cl, A, Ah, Bh, AhA);
  k_u<<<dim3(7, Mm), 64, 0, stream>>>(ctxt_vec, AhA, u);
  k_escore<<<Mm, 256, 0, stream>>>(u, ctxt_vec, cand_vec, B, scores);

  dim3 g(MC / 128, MC / 128);
  k_pairwise_mfma<<<g, 256, 0, stream>>>(Ah, Bh, P);

  // ping-pong partials: it0->ppA, it1->ppB, it2->ppA, it3->ppB, it4->ppA
  float* bufs[2] = { ppA, ppB };
  for (int it = 0; it < LBP_ITERS; ++it) {
    float* pout = bufs[it & 1];
    float* pin  = bufs[(it & 1) ^ 1];
    k_lbp<<<dim3(Mm, 2), 256, 0, stream>>>(
        P, scores, pin, pin + MC, pout, emsg, it == 0 ? 1 : 0);
  }
  // last iter (it=4) wrote ppA
  k_final2<<<(Mm + 63) / 64, 64, 0, stream>>>(
      scores, ppA, ppA + MC, pem, W1, b1, W2, b2, out);
}